// Round 10
// baseline (1590.831 us; speedup 1.0000x reference)
//
#include <hip/hip_runtime.h>
#include <math.h>

#define S   2048
#define E   4096
#define H   32
#define HD  128
#define NKEEP 205
#define NEGF -3.0e38f

typedef unsigned short ushort_t;
typedef __attribute__((ext_vector_type(8))) __bf16 bf16x8;
typedef __attribute__((ext_vector_type(4))) float f32x4;

__device__ __forceinline__ unsigned fmap(float x) {
    unsigned u = __float_as_uint(x);
    return (u & 0x80000000u) ? ~u : (u | 0x80000000u);
}
__device__ __forceinline__ ushort_t f2bf(float f) {
    unsigned u = __float_as_uint(f);
    u += 0x7FFFu + ((u >> 16) & 1u);
    return (ushort_t)(u >> 16);
}
__device__ __forceinline__ float bf2f(ushort_t h) {
    return __uint_as_float((unsigned)h << 16);
}

// async global->LDS, 16B per lane. LDS dest must be wave-uniform base +
// lane*16 -- callers pass per-thread &lds[tid*8] with tid-contiguous chunks,
// which satisfies that by construction.
__device__ __forceinline__ void gl16(const ushort_t* g, ushort_t* l) {
    __builtin_amdgcn_global_load_lds(
        (const __attribute__((address_space(1))) unsigned*)g,
        (__attribute__((address_space(3))) unsigned*)l, 16, 0, 0);
}

// ---------------------------------------------------------------------------
// fp32 -> (hi, lo) bf16 split decomposition, 8 elems/thread
// ---------------------------------------------------------------------------
__global__ __launch_bounds__(256) void decomp(const float* __restrict__ in,
                                              ushort_t* __restrict__ hi,
                                              ushort_t* __restrict__ lo)
{
    size_t i8 = ((size_t)blockIdx.x * 256 + threadIdx.x) * 8;
    float x[8];
    *(float4*)&x[0] = *(const float4*)&in[i8];
    *(float4*)&x[4] = *(const float4*)&in[i8 + 4];
    ushort_t rh[8], rl[8];
#pragma unroll
    for (int i = 0; i < 8; i++) {
        ushort_t h = f2bf(x[i]);
        rh[i] = h;
        rl[i] = f2bf(x[i] - bf2f(h));
    }
    *(uint4*)&hi[i8] = *(uint4*)rh;
    *(uint4*)&lo[i8] = *(uint4*)rl;
}

// ---------------------------------------------------------------------------
// W fp32 [K][N] -> bf16 split W^T: Wth/Wtl [N][K]  (32x32 tile transpose)
// ---------------------------------------------------------------------------
__global__ __launch_bounds__(256) void transp_decomp(const float* __restrict__ W,
                                                     ushort_t* __restrict__ Wth,
                                                     ushort_t* __restrict__ Wtl)
{
    __shared__ ushort_t th[32][34];
    __shared__ ushort_t tl[32][34];
    const int tid = threadIdx.x;
    const int k0 = blockIdx.y * 32, n0 = blockIdx.x * 32;
    const int row = tid >> 3, c4 = (tid & 7) * 4;
    float4 v = *(const float4*)&W[(size_t)(k0 + row) * E + n0 + c4];
    float x[4] = { v.x, v.y, v.z, v.w };
#pragma unroll
    for (int i = 0; i < 4; i++) {
        ushort_t h = f2bf(x[i]);
        th[row][c4 + i] = h;
        tl[row][c4 + i] = f2bf(x[i] - bf2f(h));
    }
    __syncthreads();
    ushort_t oh[4], ol[4];
#pragma unroll
    for (int i = 0; i < 4; i++) {
        oh[i] = th[c4 + i][row];
        ol[i] = tl[c4 + i][row];
    }
    *((uint2*)&Wth[(size_t)(n0 + row) * E + k0 + c4]) = *(uint2*)oh;
    *((uint2*)&Wtl[(size_t)(n0 + row) * E + k0 + c4]) = *(uint2*)ol;
}

// ---------------------------------------------------------------------------
// W fp32 [K][N] -> plain bf16 W^T [N][K]  (for Wv / Wo)
// ---------------------------------------------------------------------------
__global__ __launch_bounds__(256) void transp_cvt(const float* __restrict__ W,
                                                  ushort_t* __restrict__ Wt)
{
    __shared__ ushort_t tile[32][34];
    const int tid = threadIdx.x;
    const int k0 = blockIdx.y * 32, n0 = blockIdx.x * 32;
    const int row = tid >> 3, c4 = (tid & 7) * 4;
    float4 v = *(const float4*)&W[(size_t)(k0 + row) * E + n0 + c4];
    tile[row][c4 + 0] = f2bf(v.x);
    tile[row][c4 + 1] = f2bf(v.y);
    tile[row][c4 + 2] = f2bf(v.z);
    tile[row][c4 + 3] = f2bf(v.w);
    __syncthreads();
    ushort_t o[4] = { tile[c4 + 0][row], tile[c4 + 1][row],
                      tile[c4 + 2][row], tile[c4 + 3][row] };
    *((uint2*)&Wt[(size_t)(n0 + row) * E + k0 + c4]) = *(uint2*)o;
}

// ---------------------------------------------------------------------------
// Split-bf16 MFMA GEMM (fp32-accuracy): C = (Ah+Al) x (Bh+Bl)^T, dropping
// Al*Bl. Output as hi/lo bf16 split. 128x128 tile, BK=32.
// global_load_lds width-16 staging (linear LDS) + XCD-aware block swizzle.
// ---------------------------------------------------------------------------
__global__ __launch_bounds__(256) void gemm_split(const ushort_t* __restrict__ Ah,
                                                  const ushort_t* __restrict__ Al,
                                                  const ushort_t* __restrict__ Bh,
                                                  const ushort_t* __restrict__ Bl,
                                                  ushort_t* __restrict__ Chi,
                                                  ushort_t* __restrict__ Clo,
                                                  int M, int N, int Kd)
{
    __shared__ ushort_t AsH[128 * 32];
    __shared__ ushort_t AsL[128 * 32];
    __shared__ ushort_t BsH[128 * 32];
    __shared__ ushort_t BsL[128 * 32];
    const int tid = threadIdx.x;

    // XCD swizzle: nwg = 512 (divisible by 8) for all launches of this kernel
    const int nwg = gridDim.x * gridDim.y;
    int bid = blockIdx.y * gridDim.x + blockIdx.x;
    bid = (bid & 7) * (nwg >> 3) + (bid >> 3);
    const int m0 = (bid / gridDim.x) * 128, n0 = (bid % gridDim.x) * 128;

    const int lane = tid & 63, w = tid >> 6;
    const int wm = (w & 1) * 64, wn = (w >> 1) * 64;
    const int ll = lane & 15, lh = lane >> 4;
    const int r0 = tid >> 2, kc0 = (tid & 3) * 8;

    f32x4 acc[4][4];
#pragma unroll
    for (int i = 0; i < 4; i++)
#pragma unroll
        for (int j = 0; j < 4; j++) acc[i][j] = f32x4{0.f, 0.f, 0.f, 0.f};

    const size_t aoff = (size_t)(m0 + r0) * Kd + kc0;
    const size_t boff = (size_t)(n0 + r0) * Kd + kc0;
    const size_t roff = (size_t)64 * Kd;

    for (int k0 = 0; k0 < Kd; k0 += 32) {
        __syncthreads();
        gl16(Ah + aoff + k0,        &AsH[tid * 8]);
        gl16(Ah + aoff + roff + k0, &AsH[tid * 8 + 2048]);
        gl16(Al + aoff + k0,        &AsL[tid * 8]);
        gl16(Al + aoff + roff + k0, &AsL[tid * 8 + 2048]);
        gl16(Bh + boff + k0,        &BsH[tid * 8]);
        gl16(Bh + boff + roff + k0, &BsH[tid * 8 + 2048]);
        gl16(Bl + boff + k0,        &BsL[tid * 8]);
        gl16(Bl + boff + roff + k0, &BsL[tid * 8 + 2048]);
        __syncthreads();

        bf16x8 afh[4], afl[4], bfh[4], bfl[4];
#pragma unroll
        for (int i = 0; i < 4; i++) {
            afh[i] = *(const bf16x8*)&AsH[(wm + 16 * i + ll) * 32 + lh * 8];
            afl[i] = *(const bf16x8*)&AsL[(wm + 16 * i + ll) * 32 + lh * 8];
        }
#pragma unroll
        for (int j = 0; j < 4; j++) {
            bfh[j] = *(const bf16x8*)&BsH[(wn + 16 * j + ll) * 32 + lh * 8];
            bfl[j] = *(const bf16x8*)&BsL[(wn + 16 * j + ll) * 32 + lh * 8];
        }
#pragma unroll
        for (int i = 0; i < 4; i++)
#pragma unroll
            for (int j = 0; j < 4; j++) {
                acc[i][j] = __builtin_amdgcn_mfma_f32_16x16x32_bf16(afh[i], bfh[j], acc[i][j], 0, 0, 0);
                acc[i][j] = __builtin_amdgcn_mfma_f32_16x16x32_bf16(afh[i], bfl[j], acc[i][j], 0, 0, 0);
                acc[i][j] = __builtin_amdgcn_mfma_f32_16x16x32_bf16(afl[i], bfh[j], acc[i][j], 0, 0, 0);
            }
    }
#pragma unroll
    for (int i = 0; i < 4; i++)
#pragma unroll
        for (int j = 0; j < 4; j++)
#pragma unroll
            for (int r = 0; r < 4; r++) {
                float v = acc[i][j][r];
                ushort_t h = f2bf(v);
                ushort_t l = f2bf(v - bf2f(h));
                size_t idx = (size_t)(m0 + wm + 16 * i + lh * 4 + r) * N + (n0 + wn + 16 * j + ll);
                Chi[idx] = h;
                Clo[idx] = l;
            }
}

// ---------------------------------------------------------------------------
// Plain bf16 MFMA GEMM -> fp32 C (O projection).  gload_lds + XCD swizzle.
// ---------------------------------------------------------------------------
__global__ __launch_bounds__(256) void gemm_bf16t(const ushort_t* __restrict__ A,
                                                  const ushort_t* __restrict__ Bt,
                                                  float* __restrict__ C,
                                                  int M, int N, int Kd)
{
    __shared__ ushort_t As[128 * 32];
    __shared__ ushort_t Bs[128 * 32];
    const int tid = threadIdx.x;

    const int nwg = gridDim.x * gridDim.y;
    int bid = blockIdx.y * gridDim.x + blockIdx.x;
    bid = (bid & 7) * (nwg >> 3) + (bid >> 3);
    const int m0 = (bid / gridDim.x) * 128, n0 = (bid % gridDim.x) * 128;

    const int lane = tid & 63, w = tid >> 6;
    const int wm = (w & 1) * 64, wn = (w >> 1) * 64;
    const int ll = lane & 15, lh = lane >> 4;
    const int r0 = tid >> 2, kc0 = (tid & 3) * 8;

    f32x4 acc[4][4];
#pragma unroll
    for (int i = 0; i < 4; i++)
#pragma unroll
        for (int j = 0; j < 4; j++) acc[i][j] = f32x4{0.f, 0.f, 0.f, 0.f};

    const size_t aoff = (size_t)(m0 + r0) * Kd + kc0;
    const size_t boff = (size_t)(n0 + r0) * Kd + kc0;
    const size_t roff = (size_t)64 * Kd;

    for (int k0 = 0; k0 < Kd; k0 += 32) {
        __syncthreads();
        gl16(A + aoff + k0,         &As[tid * 8]);
        gl16(A + aoff + roff + k0,  &As[tid * 8 + 2048]);
        gl16(Bt + boff + k0,        &Bs[tid * 8]);
        gl16(Bt + boff + roff + k0, &Bs[tid * 8 + 2048]);
        __syncthreads();

        bf16x8 af[4], bfr[4];
#pragma unroll
        for (int i = 0; i < 4; i++)
            af[i] = *(const bf16x8*)&As[(wm + 16 * i + ll) * 32 + lh * 8];
#pragma unroll
        for (int j = 0; j < 4; j++)
            bfr[j] = *(const bf16x8*)&Bs[(wn + 16 * j + ll) * 32 + lh * 8];
#pragma unroll
        for (int i = 0; i < 4; i++)
#pragma unroll
            for (int j = 0; j < 4; j++)
                acc[i][j] = __builtin_amdgcn_mfma_f32_16x16x32_bf16(af[i], bfr[j], acc[i][j], 0, 0, 0);
    }
#pragma unroll
    for (int i = 0; i < 4; i++)
#pragma unroll
        for (int j = 0; j < 4; j++)
#pragma unroll
            for (int r = 0; r < 4; r++)
                C[(size_t)(m0 + wm + 16 * i + lh * 4 + r) * N + (n0 + wn + 16 * j + ll)] = acc[i][j][r];
}

// ---------------------------------------------------------------------------
// Plain bf16 MFMA GEMM -> bf16 C^T  (V projection, writes Vt[e][s] directly)
// gload_lds + XCD swizzle.
// ---------------------------------------------------------------------------
__global__ __launch_bounds__(256) void gemm_bf16_vt(const ushort_t* __restrict__ A,
                                                    const ushort_t* __restrict__ Bt,
                                                    ushort_t* __restrict__ Ct,
                                                    int M, int N, int Kd)
{
    __shared__ ushort_t As[128 * 32];
    __shared__ ushort_t Bs[128 * 32];
    const int tid = threadIdx.x;

    const int nwg = gridDim.x * gridDim.y;
    int bid = blockIdx.y * gridDim.x + blockIdx.x;
    bid = (bid & 7) * (nwg >> 3) + (bid >> 3);
    const int m0 = (bid / gridDim.x) * 128, n0 = (bid % gridDim.x) * 128;

    const int lane = tid & 63, w = tid >> 6;
    const int wm = (w & 1) * 64, wn = (w >> 1) * 64;
    const int ll = lane & 15, lh = lane >> 4;
    const int r0 = tid >> 2, kc0 = (tid & 3) * 8;

    f32x4 acc[4][4];
#pragma unroll
    for (int i = 0; i < 4; i++)
#pragma unroll
        for (int j = 0; j < 4; j++) acc[i][j] = f32x4{0.f, 0.f, 0.f, 0.f};

    const size_t aoff = (size_t)(m0 + r0) * Kd + kc0;
    const size_t boff = (size_t)(n0 + r0) * Kd + kc0;
    const size_t roff = (size_t)64 * Kd;

    for (int k0 = 0; k0 < Kd; k0 += 32) {
        __syncthreads();
        gl16(A + aoff + k0,         &As[tid * 8]);
        gl16(A + aoff + roff + k0,  &As[tid * 8 + 2048]);
        gl16(Bt + boff + k0,        &Bs[tid * 8]);
        gl16(Bt + boff + roff + k0, &Bs[tid * 8 + 2048]);
        __syncthreads();

        bf16x8 af[4], bfr[4];
#pragma unroll
        for (int i = 0; i < 4; i++)
            af[i] = *(const bf16x8*)&As[(wm + 16 * i + ll) * 32 + lh * 8];
#pragma unroll
        for (int j = 0; j < 4; j++)
            bfr[j] = *(const bf16x8*)&Bs[(wn + 16 * j + ll) * 32 + lh * 8];
#pragma unroll
        for (int i = 0; i < 4; i++)
#pragma unroll
            for (int j = 0; j < 4; j++)
                acc[i][j] = __builtin_amdgcn_mfma_f32_16x16x32_bf16(af[i], bfr[j], acc[i][j], 0, 0, 0);
    }
#pragma unroll
    for (int i = 0; i < 4; i++)
#pragma unroll
        for (int j = 0; j < 4; j++) {
            ushort_t o4[4];
#pragma unroll
            for (int r = 0; r < 4; r++) o4[r] = f2bf(acc[i][j][r]);
            size_t n = n0 + wn + 16 * j + ll;
            size_t m = m0 + wm + 16 * i + lh * 4;
            *(uint2*)&Ct[n * M + m] = *(uint2*)o4;
        }
}

// ---------------------------------------------------------------------------
// RoPE from hi/lo split Q/K -> bf16 QR/KR
// ---------------------------------------------------------------------------
__global__ __launch_bounds__(256) void rope_split(const ushort_t* __restrict__ Qh,
                                                  const ushort_t* __restrict__ Ql,
                                                  const ushort_t* __restrict__ Kh,
                                                  const ushort_t* __restrict__ Kl,
                                                  ushort_t* __restrict__ QR,
                                                  ushort_t* __restrict__ KR)
{
    int idx = blockIdx.x * 256 + threadIdx.x;
    int s   = idx >> 11;
    int rem = idx & 2047;
    int h   = rem >> 6;
    int d   = rem & 63;
    float inv = exp2f(-0.20762050593046f * (float)d);
    float ang = (float)s * inv;
    float sn, cs;
    sincosf(ang, &sn, &cs);
    size_t base = (size_t)s * E + h * HD;
    float q0 = bf2f(Qh[base + d])      + bf2f(Ql[base + d]);
    float q1 = bf2f(Qh[base + d + 64]) + bf2f(Ql[base + d + 64]);
    QR[base + d]      = f2bf(q0 * cs - q1 * sn);
    QR[base + d + 64] = f2bf(q1 * cs + q0 * sn);
    float k0 = bf2f(Kh[base + d])      + bf2f(Kl[base + d]);
    float k1 = bf2f(Kh[base + d + 64]) + bf2f(Kl[base + d + 64]);
    KR[base + d]      = f2bf(k0 * cs - k1 * sn);
    KR[base + d + 64] = f2bf(k1 * cs + k0 * sn);
}

// ---------------------------------------------------------------------------
// Selection v9: 16 q-rows/block, 16 waves (1024 thr). u16 scores in LDS.
//  - register-resident row for the radix passes: each radix wave loads its
//    2048-col row once via <=8 ds_read_b64 (4 u16/lane; 2-way bank aliasing
//    = free) and runs pass-0 ballot-match + pass-1 atomics from VGPRs.
//    Removes 2 full 17-iteration LDS latency sweeps per row. Histogram
//    passes are order-agnostic, so the stride-4 col permutation is safe.
//  - tie-break and mask phases keep their LDS-ordered access (col-ordered
//    slot assignment / ballots required); demotion writes remain in LDS and
//    are seen by the mask phase as before.
// ---------------------------------------------------------------------------
__global__ __launch_bounds__(1024, 8) void select_u16(const ushort_t* __restrict__ Qhi,
                                                      const ushort_t* __restrict__ Qlo,
                                                      const ushort_t* __restrict__ Khi,
                                                      const ushort_t* __restrict__ Klo,
                                                      unsigned* __restrict__ Mask)
{
    __shared__ ushort_t sc16[16 * 2048];   // 64 KB; 8B-block xor-swizzle per row
    __shared__ unsigned hist[16][256];     // 16 KB; reused as tie-col list

    const int tid = threadIdx.x;
    const int w = tid >> 6, lane = tid & 63;
    const int ll = lane & 15, lh = lane >> 4;
    const int q0 = blockIdx.y * 16;        // grid transposed: y = q-tile
    const int h  = blockIdx.x;             //                  x = head

    // Q B-frags for rows q0+ll (hi/lo)
    bf16x8 bqh[4], bql[4];
    {
        const size_t qb = (size_t)(q0 + ll) * E + h * HD;
#pragma unroll
        for (int ks = 0; ks < 4; ks++) {
            bqh[ks] = *(const bf16x8*)&Qhi[qb + ks * 32 + lh * 8];
            bql[ks] = *(const bf16x8*)&Qlo[qb + ks * 32 + lh * 8];
        }
    }

    // ---- score phase (no barriers): wave w covers kv strip [cb+16w, +16) ----
    const int qend = q0 + 16;
    for (int cb = 0; cb < qend; cb += 256) {
        const size_t kbase = (size_t)(cb + w * 16 + ll) * E + h * HD;
        f32x4 acc = f32x4{0.f, 0.f, 0.f, 0.f};
#pragma unroll
        for (int ks = 0; ks < 4; ks++) {
            bf16x8 akh = *(const bf16x8*)&Khi[kbase + ks * 32 + lh * 8];
            bf16x8 akl = *(const bf16x8*)&Klo[kbase + ks * 32 + lh * 8];
            acc = __builtin_amdgcn_mfma_f32_16x16x32_bf16(akh, bqh[ks], acc, 0, 0, 0);
            acc = __builtin_amdgcn_mfma_f32_16x16x32_bf16(akh, bql[ks], acc, 0, 0, 0);
            acc = __builtin_amdgcn_mfma_f32_16x16x32_bf16(akl, bqh[ks], acc, 0, 0, 0);
        }
        // C-layout: q col = ll, kv row = w*16 + lh*4 + r
        const int qrow_g = q0 + ll;
        const int col0 = cb + w * 16 + lh * 4;
        ushort_t v4[4];
#pragma unroll
        for (int r = 0; r < 4; r++) {
            int col = col0 + r;
            v4[r] = (col <= qrow_g) ? (ushort_t)(fmap(acc[r]) >> 16) : (ushort_t)0;
        }
        const int blk = col0 >> 2;
        *(uint2*)&sc16[ll * 2048 + ((blk ^ (ll & 7)) << 2)] = *(uint2*)v4;
    }
    __syncthreads();

    // ---- radix + tie + mask: wave w owns q-row w ----
    unsigned* hw = hist[w];
    {
        const int qq = w;
        const int qrow = q0 + qq;
        ushort_t* srow = &sc16[qq * 2048];
        const int swz = qq & 7;
        const int nch = (qrow >> 6) + 1;   // valid 64-col chunks
        const int nb64 = (nch + 3) >> 2;   // b64 sweeps, 256 cols each
        unsigned thr = 1u;
        if (qrow + 1 > NKEEP) {
            // load row into regs: rv[i] holds cols 4*(lane+64i)..+3
            // (cols beyond qrow are score-phase-zeroed -> skipped as sentinel)
            uint2 rv[8];
#pragma unroll
            for (int i = 0; i < 8; i++) {
                rv[i] = make_uint2(0u, 0u);
                if (i < nb64) {
                    int blk = lane + (i << 6);
                    rv[i] = *(const uint2*)&srow[(blk ^ swz) << 2];
                }
            }
            unsigned p = 0u, need = NKEEP;
#pragma unroll
            for (int pass = 0; pass < 2; pass++) {
                *(uint4*)&hw[lane * 4] = make_uint4(0u, 0u, 0u, 0u);
                __threadfence_block();
                if (pass == 0) {
                    // wave-aggregated high-byte histogram from regs;
                    // one atomicAdd lane-op per unique digit.
#pragma unroll
                    for (int i = 0; i < 8; i++) {
                        if (i < nb64) {
                            unsigned vv[4] = { rv[i].x & 0xFFFFu, rv[i].x >> 16,
                                               rv[i].y & 0xFFFFu, rv[i].y >> 16 };
#pragma unroll
                            for (int j = 0; j < 4; j++) {
                                unsigned v = vv[j];
                                unsigned d = v >> 8;
                                bool part = (v != 0u);
                                unsigned long long mm = __ballot(part);
#pragma unroll
                                for (int b = 0; b < 8; b++) {
                                    unsigned long long bb = __ballot((d >> b) & 1u);
                                    mm &= ((d >> b) & 1u) ? bb : ~bb;
                                }
                                if (part && ((mm & ((1ull << lane) - 1ull)) == 0ull))
                                    atomicAdd(&hw[d], (unsigned)__popcll(mm));
                            }
                        }
                    }
                } else {
#pragma unroll
                    for (int i = 0; i < 8; i++) {
                        if (i < nb64) {
                            unsigned vv[4] = { rv[i].x & 0xFFFFu, rv[i].x >> 16,
                                               rv[i].y & 0xFFFFu, rv[i].y >> 16 };
#pragma unroll
                            for (int j = 0; j < 4; j++) {
                                unsigned v = vv[j];
                                if ((v >> 8) == p) atomicAdd(&hw[v & 255u], 1u);
                            }
                        }
                    }
                }
                __threadfence_block();
                uint4 hv = *(const uint4*)&hw[lane * 4];
                unsigned t3 = hv.w, t2 = t3 + hv.z, t1 = t2 + hv.y, t0 = t1 + hv.x;
                unsigned sv = t0, run = sv;
#pragma unroll
                for (int off = 1; off < 64; off <<= 1) {
                    unsigned o = __shfl_down(run, off);
                    if (lane + off < 64) run += o;
                }
                const unsigned nxt = run - sv;
                unsigned tj[4] = { t0, t1, t2, t3 };
                bool m = false; unsigned nb = 0u, nn = 0u;
#pragma unroll
                for (int j = 0; j < 4; j++) {
                    unsigned sb  = nxt + tj[j];
                    unsigned sb1 = nxt + ((j < 3) ? tj[j + 1] : 0u);
                    if (!m && need <= sb && need > sb1) {
                        m = true; nb = (unsigned)(lane * 4 + j); nn = need - sb1;
                    }
                }
                unsigned long long bal = __ballot(m);
                int src = __ffsll(bal) - 1;
                p    = (p << 8) | __shfl(nb, src);
                need = __shfl(nn, src);
            }
            thr = p;
            const unsigned count_eq = hw[p & 255u];   // pass-2 hist persists
            const unsigned t_need = need;
            if (count_eq > t_need) {
                const bool ovf = (count_eq > 64);
                ushort_t* tiecol = (ushort_t*)hw;     // hist no longer needed
                unsigned tcnt = 0;
                for (int i = 0; i < nch; i++) {
                    int c = lane + (i << 6);
                    int adr = (((c >> 2) ^ swz) << 2) | (c & 3);
                    bool eq = (srow[adr] == (ushort_t)thr);
                    unsigned long long bal = __ballot(eq);
                    if (eq) {
                        unsigned slot = tcnt + (unsigned)__popcll(bal & ((1ull << lane) - 1ull));
                        if (ovf) {
                            if (slot >= t_need) srow[adr] = (ushort_t)(thr - 1u);  // keep-first-by-col fallback
                        } else {
                            tiecol[slot] = (ushort_t)c;
                        }
                    }
                    tcnt += (unsigned)__popcll(bal);
                }
                if (!ovf) {
                    __threadfence_block();
                    const int ntie = (int)count_eq;
                    int mycol = (lane < ntie) ? (int)tiecol[lane] : 0;
                    float myval = 0.f;
                    const size_t qb = (size_t)qrow * E + h * HD;
                    const float qv0 = bf2f(Qhi[qb + lane])      + bf2f(Qlo[qb + lane]);
                    const float qv1 = bf2f(Qhi[qb + lane + 64]) + bf2f(Qlo[qb + lane + 64]);
                    for (int tt = 0; tt < ntie; tt++) {
                        const size_t kb = (size_t)tiecol[tt] * E + h * HD;
                        float kv0 = bf2f(Khi[kb + lane])      + bf2f(Klo[kb + lane]);
                        float kv1 = bf2f(Khi[kb + lane + 64]) + bf2f(Klo[kb + lane + 64]);
                        float pp = qv0 * kv0 + qv1 * kv1;
#pragma unroll
                        for (int off = 1; off < 64; off <<= 1) pp += __shfl_xor(pp, off);
                        if (lane == tt) myval = pp;
                    }
                    int rank = 0;
                    for (int j = 0; j < ntie; j++) {
                        float vj = __shfl(myval, j);
                        int   cj = __shfl(mycol, j);
                        if (lane < ntie && ((vj > myval) || (vj == myval && cj < mycol))) rank++;
                    }
                    if (lane < ntie && rank >= (int)t_need) {
                        int adr = (((mycol >> 2) ^ swz) << 2) | (mycol & 3);
                        srow[adr] = (ushort_t)(thr - 1u);
                    }
                    __threadfence_block();
                }
            }
        }
        // mask write: keep = score >= thr (exactly NKEEP kept for radix rows)
        const size_t mbase = ((size_t)h * S + qrow) * 64;
        for (int ci = 0; ci < nch; ci++) {
            int c = ci * 64 + lane;
            int adr = (((c >> 2) ^ swz) << 2) | (c & 3);
            bool keep = (unsigned)srow[adr] >= thr;
            unsigned long long bm = __ballot(keep);
            if (lane == 0) {
                Mask[mbase + 2 * ci]     = (unsigned)bm;
                Mask[mbase + 2 * ci + 1] = (unsigned)(bm >> 32);
            }
        }
        {   // zero tail chunks (cols > qrow): one pass, lanes cover chunks
            int ci = nch + lane;
            if (ci < 32) {
                Mask[mbase + 2 * ci]     = 0u;
                Mask[mbase + 2 * ci + 1] = 0u;
            }
        }
    }
}

// ---------------------------------------------------------------------------
// MFMA flash attention (unchanged)
// ---------------------------------------------------------------------------
__global__ __launch_bounds__(256) void attn_mfma(const ushort_t* __restrict__ QR,
                                                 const ushort_t* __restrict__ KR,
                                                 const ushort_t* __restrict__ Vt,
                                                 const unsigned* __restrict__ Mask,
                                                 ushort_t* __restrict__ O)
{
    __shared__ ushort_t Qs[64][136];
    __shared__ ushort_t Ks[64][136];
    __shared__ ushort_t Vs[128][72];
    __shared__ unsigned long long Ms[64];

    const int tid = threadIdx.x;
    const int w = tid >> 6, lane = tid & 63;
    const int ll = lane & 15, lh = lane >> 4;
    const int q0 = blockIdx.x * 64;
    const int h  = blockIdx.y;

#pragma unroll
    for (int i = 0; i < 4; i++) {
        int idx = tid + i * 256;
        int r = idx >> 4, c8 = (idx & 15) * 8;
        *(uint4*)&Qs[r][c8] = *(const uint4*)&QR[(size_t)(q0 + r) * E + h * HD + c8];
    }

    f32x4 Oa[8];
#pragma unroll
    for (int i = 0; i < 8; i++) Oa[i] = f32x4{0.f, 0.f, 0.f, 0.f};
    float mrun = NEGF, lrun = 0.f;
    const float SCL = 0.08838834764831845f * 1.44269504088896f;

    for (int cb = 0; cb <= q0; cb += 64) {
        __syncthreads();
#pragma unroll
        for (int i = 0; i < 4; i++) {
            int idx = tid + i * 256;
            int r = idx >> 4, c8 = (idx & 15) * 8;
            *(uint4*)&Ks[r][c8] = *(const uint4*)&KR[(size_t)(cb + r) * E + h * HD + c8];
        }
#pragma unroll
        for (int i = 0; i < 4; i++) {
            int idx = tid + i * 256;
            int r = idx >> 3, c8 = (idx & 7) * 8;
            *(uint4*)&Vs[r][c8] = *(const uint4*)&Vt[((size_t)h * HD + r) * S + cb + c8];
        }
        if (tid < 64)
            Ms[tid] = *(const unsigned long long*)&Mask[((size_t)h * S + q0 + tid) * 64 + (cb >> 5)];
        __syncthreads();

        f32x4 Sc[4];
#pragma unroll
        for (int t = 0; t < 4; t++) Sc[t] = f32x4{0.f, 0.f, 0.f, 0.f};
#pragma unroll
        for (int kk = 0; kk < 4; kk++) {
            bf16x8 bq = *(const bf16x8*)&Qs[16 * w + ll][kk * 32 + lh * 8];
#pragma unroll
            for (int t = 0; t < 4; t++) {
                bf16x8 ak = *(const bf16x8*)&Ks[t * 16 + ll][kk * 32 + lh * 8];
                Sc[t] = __builtin_amdgcn_mfma_f32_16x16x32_bf16(ak, bq, Sc[t], 0, 0, 0);
            }
        }

        unsigned long long mrow = Ms[16 * w + ll];
        float sc[4][4];
        float cm = NEGF;
#pragma unroll
        for (int t = 0; t < 4; t++)
#pragma unroll
            for (int r = 0; r < 4; r++) {
                int bit = t * 16 + lh * 4 + r;
                float v = ((mrow >> bit) & 1ull) ? Sc[t][r] * SCL : NEGF;
                sc[t][r] = v;
                cm = fmaxf(cm, v);
            }
        cm = fmaxf(cm, __shfl_xor(cm, 16));
        cm = fmaxf(cm, __shfl_xor(cm, 32));
        float mnew = fmaxf(mrun, cm);
        float alpha = exp2f(mrun - mnew);
        mrun = mnew;
        lrun *= alpha;

        unsigned pk[4][2];
#pragma unroll
        for (int t = 0; t < 4; t++) {
            float p0 = (sc[t][0] > -1e37f) ? exp2f(sc[t][0] - mnew) : 0.f;
            float p1 = (sc[t][1] > -1e37f) ? exp2f(sc[t][1] - mnew) : 0.f;
            float p2 = (sc[t][2] > -1e37f) ? exp2f(sc[t][2] - mnew) : 0.f;
            float p3 = (sc[t][3] > -1e37f) ? exp2f(sc[t][3] - mnew) : 0.f;
            lrun += p0 + p1 + p2 + p3;
            pk[t][0] = (unsigned)f2bf(p0) | ((unsigned)f2bf(p1) << 16);
            pk[t][1] = (unsigned)f2bf(p2) | ((unsigned)f2bf(p3) << 16);
        }
#pragma unroll
        for (int dt = 0; dt < 8; dt++) Oa[dt] *= alpha;

#pragma unroll
        for (int ks = 0; ks < 2; ks++) {
            union { unsigned u[4]; bf16x8 v; } bu;
#pragma unroll
            for (int jj = 0; jj < 4; jj++) {
                int rp  = jj & 1;
                int src = ll + 16 * ((lh & 1) * 2 + (jj >> 1));
                unsigned v0 = __shfl(pk[ks * 2][rp], src);
                unsigned v1 = __shfl(pk[ks * 2 + 1][rp], src);
                bu.u[jj] = (lh >> 1) ? v1 : v0;
            }
            bf16x8 bp = bu.v;
#pragma unroll
            for (int dt = 0; dt < 8; dt++) {
                bf16x8 av = *(const bf16x8*)&Vs[dt * 16 + ll][ks * 32 + lh * 8];
                Oa[dt] = __builtin_amdgcn_mfma_f32_16x16x32_bf16(av, bp, Oa[dt], 0, 0, 0);
            }
        }
    }

    lrun += __shfl_xor(lrun, 16);
    lrun += __shfl_xor(lrun, 32);
    float linv = 1.0f / lrun;

    __syncthreads();
    ushort_t* tb = &Ks[16 * w][0];
#pragma unroll
    for (int dt = 0; dt < 8; dt++)
#pragma unroll
        for (int r = 0; r < 4; r++)
            tb[ll * 136 + dt * 16 + lh * 4 + r] = f2bf(Oa[dt][r] * linv);
#pragma unroll
    for (int i = 0; i < 4; i++) {
        int idx = lane + 64 * i;
        int r = idx >> 4, c8 = (idx & 15) * 8;
        uint4 vv = *(const uint4*)&tb[r * 136 + c8];
        *(uint4*)&O[(size_t)(q0 + 16 * w + r) * E + h * HD + c8] = vv;
    }
}

// ---------------------------------------------------------------------------
extern "C" void kernel_launch(void* const* d_in, const int* in_sizes, int n_in,
                              void* d_out, int out_size, void* d_ws, size_t ws_size,
                              hipStream_t stream)
{
    (void)in_sizes; (void)n_in; (void)out_size; (void)ws_size;
    const float* hidden = (const float*)d_in[0];
    const float* Wq = (const float*)d_in[1];
    const float* Wk = (const float*)d_in[2];
    const float* Wv = (const float*)d_in[3];
    const float* Wo = (const float*)d_in[4];

    float* ws = (float*)d_ws;
    const size_t SE = (size_t)S * E;   // 8388608
    ushort_t* Hhi  = (ushort_t*)ws;                      // [0,   .5SE)
    ushort_t* Hlo  = (ushort_t*)(ws + SE / 2);           // [.5,  1SE)  -> later Obf
    ushort_t* WtH  = (ushort_t*)(ws + SE);               // [1,   2SE)  -> later Wt
    ushort_t* WtL  = (ushort_t*)(ws + 2 * SE);           // [2,   3SE)  -> later QR/KR
    ushort_t* Qhi  = (ushort_t*)(ws + 3 * SE);           // [3,  3.5SE)
    ushort_t* Qlo  = (ushort_t*)(ws + 3 * SE + SE / 2);  // [3.5, 4SE)
    ushort_t* Khi  = (ushort_t*)(ws + 4 * SE);           // [4,  4.5SE)
    ushort_t* Klo  = (ushort_t*)(ws + 4 * SE + SE / 2);  // [4.5, 5SE)
    unsigned* Maskb= (unsigned*)(ws + 5 * SE);           // [5,  5.5SE)
    ushort_t* Vtbf = (ushort_t*)(ws + 5 * SE + SE / 2);  // [5.5, 6SE)
    ushort_t* QRbf = WtL;
    ushort_t* KRbf = (ushort_t*)(ws + 2 * SE + SE / 2);
    ushort_t* Obf  = Hlo;
    ushort_t* Wt   = WtH;
    // total = 6 SE floats = 201 MB

    dim3 gg(E / 128, S / 128);           // (32,16) -> 512 blocks, %8==0
    dim3 gt(E / 32, E / 32);             // (128,128)

    decomp<<<SE / 2048, 256, 0, stream>>>(hidden, Hhi, Hlo);

    transp_decomp<<<gt, 256, 0, stream>>>(Wq, WtH, WtL);
    gemm_split<<<gg, 256, 0, stream>>>(Hhi, Hlo, WtH, WtL, Qhi, Qlo, S, E, E);
    transp_decomp<<<gt, 256, 0, stream>>>(Wk, WtH, WtL);
    gemm_split<<<gg, 256, 0, stream>>>(Hhi, Hlo, WtH, WtL, Khi, Klo, S, E, E);

    select_u16<<<dim3(H, S / 16), 1024, 0, stream>>>(Qhi, Qlo, Khi, Klo, Maskb);

    rope_split<<<(S * 2048) / 256, 256, 0, stream>>>(Qhi, Qlo, Khi, Klo, QRbf, KRbf);

    transp_cvt<<<gt, 256, 0, stream>>>(Wv, Wt);
    gemm_bf16_vt<<<gg, 256, 0, stream>>>(Hhi, Wt, Vtbf, S, E, E);

    attn_mfma<<<dim3(S / 64, H), 256, 0, stream>>>(QRbf, KRbf, Vtbf, Maskb, Obf);

    transp_cvt<<<gt, 256, 0, stream>>>(Wo, Wt);
    gemm_bf16t<<<gg, 256, 0, stream>>>(Obf, Wt, (float*)d_out, S, E, E);
}

// Round 13
// 1582.210 us; speedup vs baseline: 1.0054x; 1.0054x over previous
//
#include <hip/hip_runtime.h>
#include <math.h>

#define S   2048
#define E   4096
#define H   32
#define HD  128
#define NKEEP 205
#define NEGF -3.0e38f

typedef unsigned short ushort_t;
typedef __attribute__((ext_vector_type(8))) __bf16 bf16x8;
typedef __attribute__((ext_vector_type(4))) float f32x4;

__device__ __forceinline__ unsigned fmap(float x) {
    unsigned u = __float_as_uint(x);
    return (u & 0x80000000u) ? ~u : (u | 0x80000000u);
}
__device__ __forceinline__ ushort_t f2bf(float f) {
    unsigned u = __float_as_uint(f);
    u += 0x7FFFu + ((u >> 16) & 1u);
    return (ushort_t)(u >> 16);
}
__device__ __forceinline__ float bf2f(ushort_t h) {
    return __uint_as_float((unsigned)h << 16);
}

// async global->LDS, 16B per lane. LDS dest must be wave-uniform base +
// lane*16 -- callers pass per-thread &lds[tid*8] with tid-contiguous chunks,
// which satisfies that by construction.
__device__ __forceinline__ void gl16(const ushort_t* g, ushort_t* l) {
    __builtin_amdgcn_global_load_lds(
        (const __attribute__((address_space(1))) unsigned*)g,
        (__attribute__((address_space(3))) unsigned*)l, 16, 0, 0);
}

// ---------------------------------------------------------------------------
// fp32 -> (hi, lo) bf16 split decomposition, 8 elems/thread
// ---------------------------------------------------------------------------
__global__ __launch_bounds__(256) void decomp(const float* __restrict__ in,
                                              ushort_t* __restrict__ hi,
                                              ushort_t* __restrict__ lo)
{
    size_t i8 = ((size_t)blockIdx.x * 256 + threadIdx.x) * 8;
    float x[8];
    *(float4*)&x[0] = *(const float4*)&in[i8];
    *(float4*)&x[4] = *(const float4*)&in[i8 + 4];
    ushort_t rh[8], rl[8];
#pragma unroll
    for (int i = 0; i < 8; i++) {
        ushort_t h = f2bf(x[i]);
        rh[i] = h;
        rl[i] = f2bf(x[i] - bf2f(h));
    }
    *(uint4*)&hi[i8] = *(uint4*)rh;
    *(uint4*)&lo[i8] = *(uint4*)rl;
}

// ---------------------------------------------------------------------------
// W fp32 [K][N] -> bf16 split W^T: Wth/Wtl [N][K]  (32x32 tile transpose)
// ---------------------------------------------------------------------------
__global__ __launch_bounds__(256) void transp_decomp(const float* __restrict__ W,
                                                     ushort_t* __restrict__ Wth,
                                                     ushort_t* __restrict__ Wtl)
{
    __shared__ ushort_t th[32][34];
    __shared__ ushort_t tl[32][34];
    const int tid = threadIdx.x;
    const int k0 = blockIdx.y * 32, n0 = blockIdx.x * 32;
    const int row = tid >> 3, c4 = (tid & 7) * 4;
    float4 v = *(const float4*)&W[(size_t)(k0 + row) * E + n0 + c4];
    float x[4] = { v.x, v.y, v.z, v.w };
#pragma unroll
    for (int i = 0; i < 4; i++) {
        ushort_t h = f2bf(x[i]);
        th[row][c4 + i] = h;
        tl[row][c4 + i] = f2bf(x[i] - bf2f(h));
    }
    __syncthreads();
    ushort_t oh[4], ol[4];
#pragma unroll
    for (int i = 0; i < 4; i++) {
        oh[i] = th[c4 + i][row];
        ol[i] = tl[c4 + i][row];
    }
    *((uint2*)&Wth[(size_t)(n0 + row) * E + k0 + c4]) = *(uint2*)oh;
    *((uint2*)&Wtl[(size_t)(n0 + row) * E + k0 + c4]) = *(uint2*)ol;
}

// ---------------------------------------------------------------------------
// W fp32 [K][N] -> plain bf16 W^T [N][K]  (for Wv / Wo)
// ---------------------------------------------------------------------------
__global__ __launch_bounds__(256) void transp_cvt(const float* __restrict__ W,
                                                  ushort_t* __restrict__ Wt)
{
    __shared__ ushort_t tile[32][34];
    const int tid = threadIdx.x;
    const int k0 = blockIdx.y * 32, n0 = blockIdx.x * 32;
    const int row = tid >> 3, c4 = (tid & 7) * 4;
    float4 v = *(const float4*)&W[(size_t)(k0 + row) * E + n0 + c4];
    tile[row][c4 + 0] = f2bf(v.x);
    tile[row][c4 + 1] = f2bf(v.y);
    tile[row][c4 + 2] = f2bf(v.z);
    tile[row][c4 + 3] = f2bf(v.w);
    __syncthreads();
    ushort_t o[4] = { tile[c4 + 0][row], tile[c4 + 1][row],
                      tile[c4 + 2][row], tile[c4 + 3][row] };
    *((uint2*)&Wt[(size_t)(n0 + row) * E + k0 + c4]) = *(uint2*)o;
}

// ---------------------------------------------------------------------------
// Split-bf16 MFMA GEMM (fp32-accuracy): C = (Ah+Al) x (Bh+Bl)^T, dropping
// Al*Bl. Output as hi/lo bf16 split. 128x128 tile, BK=32.
// global_load_lds width-16 staging (linear LDS) + XCD-aware block swizzle.
// ---------------------------------------------------------------------------
__global__ __launch_bounds__(256) void gemm_split(const ushort_t* __restrict__ Ah,
                                                  const ushort_t* __restrict__ Al,
                                                  const ushort_t* __restrict__ Bh,
                                                  const ushort_t* __restrict__ Bl,
                                                  ushort_t* __restrict__ Chi,
                                                  ushort_t* __restrict__ Clo,
                                                  int M, int N, int Kd)
{
    __shared__ ushort_t AsH[128 * 32];
    __shared__ ushort_t AsL[128 * 32];
    __shared__ ushort_t BsH[128 * 32];
    __shared__ ushort_t BsL[128 * 32];
    const int tid = threadIdx.x;

    // XCD swizzle: nwg = 512 (divisible by 8) for all launches of this kernel
    const int nwg = gridDim.x * gridDim.y;
    int bid = blockIdx.y * gridDim.x + blockIdx.x;
    bid = (bid & 7) * (nwg >> 3) + (bid >> 3);
    const int m0 = (bid / gridDim.x) * 128, n0 = (bid % gridDim.x) * 128;

    const int lane = tid & 63, w = tid >> 6;
    const int wm = (w & 1) * 64, wn = (w >> 1) * 64;
    const int ll = lane & 15, lh = lane >> 4;
    const int r0 = tid >> 2, kc0 = (tid & 3) * 8;

    f32x4 acc[4][4];
#pragma unroll
    for (int i = 0; i < 4; i++)
#pragma unroll
        for (int j = 0; j < 4; j++) acc[i][j] = f32x4{0.f, 0.f, 0.f, 0.f};

    const size_t aoff = (size_t)(m0 + r0) * Kd + kc0;
    const size_t boff = (size_t)(n0 + r0) * Kd + kc0;
    const size_t roff = (size_t)64 * Kd;

    for (int k0 = 0; k0 < Kd; k0 += 32) {
        __syncthreads();
        gl16(Ah + aoff + k0,        &AsH[tid * 8]);
        gl16(Ah + aoff + roff + k0, &AsH[tid * 8 + 2048]);
        gl16(Al + aoff + k0,        &AsL[tid * 8]);
        gl16(Al + aoff + roff + k0, &AsL[tid * 8 + 2048]);
        gl16(Bh + boff + k0,        &BsH[tid * 8]);
        gl16(Bh + boff + roff + k0, &BsH[tid * 8 + 2048]);
        gl16(Bl + boff + k0,        &BsL[tid * 8]);
        gl16(Bl + boff + roff + k0, &BsL[tid * 8 + 2048]);
        __syncthreads();

        bf16x8 afh[4], afl[4], bfh[4], bfl[4];
#pragma unroll
        for (int i = 0; i < 4; i++) {
            afh[i] = *(const bf16x8*)&AsH[(wm + 16 * i + ll) * 32 + lh * 8];
            afl[i] = *(const bf16x8*)&AsL[(wm + 16 * i + ll) * 32 + lh * 8];
        }
#pragma unroll
        for (int j = 0; j < 4; j++) {
            bfh[j] = *(const bf16x8*)&BsH[(wn + 16 * j + ll) * 32 + lh * 8];
            bfl[j] = *(const bf16x8*)&BsL[(wn + 16 * j + ll) * 32 + lh * 8];
        }
#pragma unroll
        for (int i = 0; i < 4; i++)
#pragma unroll
            for (int j = 0; j < 4; j++) {
                acc[i][j] = __builtin_amdgcn_mfma_f32_16x16x32_bf16(afh[i], bfh[j], acc[i][j], 0, 0, 0);
                acc[i][j] = __builtin_amdgcn_mfma_f32_16x16x32_bf16(afh[i], bfl[j], acc[i][j], 0, 0, 0);
                acc[i][j] = __builtin_amdgcn_mfma_f32_16x16x32_bf16(afl[i], bfh[j], acc[i][j], 0, 0, 0);
            }
    }
#pragma unroll
    for (int i = 0; i < 4; i++)
#pragma unroll
        for (int j = 0; j < 4; j++)
#pragma unroll
            for (int r = 0; r < 4; r++) {
                float v = acc[i][j][r];
                ushort_t h = f2bf(v);
                ushort_t l = f2bf(v - bf2f(h));
                size_t idx = (size_t)(m0 + wm + 16 * i + lh * 4 + r) * N + (n0 + wn + 16 * j + ll);
                Chi[idx] = h;
                Clo[idx] = l;
            }
}

// ---------------------------------------------------------------------------
// Plain bf16 MFMA GEMM -> fp32 C (O projection).  gload_lds + XCD swizzle.
// ---------------------------------------------------------------------------
__global__ __launch_bounds__(256) void gemm_bf16t(const ushort_t* __restrict__ A,
                                                  const ushort_t* __restrict__ Bt,
                                                  float* __restrict__ C,
                                                  int M, int N, int Kd)
{
    __shared__ ushort_t As[128 * 32];
    __shared__ ushort_t Bs[128 * 32];
    const int tid = threadIdx.x;

    const int nwg = gridDim.x * gridDim.y;
    int bid = blockIdx.y * gridDim.x + blockIdx.x;
    bid = (bid & 7) * (nwg >> 3) + (bid >> 3);
    const int m0 = (bid / gridDim.x) * 128, n0 = (bid % gridDim.x) * 128;

    const int lane = tid & 63, w = tid >> 6;
    const int wm = (w & 1) * 64, wn = (w >> 1) * 64;
    const int ll = lane & 15, lh = lane >> 4;
    const int r0 = tid >> 2, kc0 = (tid & 3) * 8;

    f32x4 acc[4][4];
#pragma unroll
    for (int i = 0; i < 4; i++)
#pragma unroll
        for (int j = 0; j < 4; j++) acc[i][j] = f32x4{0.f, 0.f, 0.f, 0.f};

    const size_t aoff = (size_t)(m0 + r0) * Kd + kc0;
    const size_t boff = (size_t)(n0 + r0) * Kd + kc0;
    const size_t roff = (size_t)64 * Kd;

    for (int k0 = 0; k0 < Kd; k0 += 32) {
        __syncthreads();
        gl16(A + aoff + k0,         &As[tid * 8]);
        gl16(A + aoff + roff + k0,  &As[tid * 8 + 2048]);
        gl16(Bt + boff + k0,        &Bs[tid * 8]);
        gl16(Bt + boff + roff + k0, &Bs[tid * 8 + 2048]);
        __syncthreads();

        bf16x8 af[4], bfr[4];
#pragma unroll
        for (int i = 0; i < 4; i++)
            af[i] = *(const bf16x8*)&As[(wm + 16 * i + ll) * 32 + lh * 8];
#pragma unroll
        for (int j = 0; j < 4; j++)
            bfr[j] = *(const bf16x8*)&Bs[(wn + 16 * j + ll) * 32 + lh * 8];
#pragma unroll
        for (int i = 0; i < 4; i++)
#pragma unroll
            for (int j = 0; j < 4; j++)
                acc[i][j] = __builtin_amdgcn_mfma_f32_16x16x32_bf16(af[i], bfr[j], acc[i][j], 0, 0, 0);
    }
#pragma unroll
    for (int i = 0; i < 4; i++)
#pragma unroll
        for (int j = 0; j < 4; j++)
#pragma unroll
            for (int r = 0; r < 4; r++)
                C[(size_t)(m0 + wm + 16 * i + lh * 4 + r) * N + (n0 + wn + 16 * j + ll)] = acc[i][j][r];
}

// ---------------------------------------------------------------------------
// Plain bf16 MFMA GEMM -> bf16 C^T  (V projection, writes Vt[e][s] directly)
// gload_lds + XCD swizzle.
// ---------------------------------------------------------------------------
__global__ __launch_bounds__(256) void gemm_bf16_vt(const ushort_t* __restrict__ A,
                                                    const ushort_t* __restrict__ Bt,
                                                    ushort_t* __restrict__ Ct,
                                                    int M, int N, int Kd)
{
    __shared__ ushort_t As[128 * 32];
    __shared__ ushort_t Bs[128 * 32];
    const int tid = threadIdx.x;

    const int nwg = gridDim.x * gridDim.y;
    int bid = blockIdx.y * gridDim.x + blockIdx.x;
    bid = (bid & 7) * (nwg >> 3) + (bid >> 3);
    const int m0 = (bid / gridDim.x) * 128, n0 = (bid % gridDim.x) * 128;

    const int lane = tid & 63, w = tid >> 6;
    const int wm = (w & 1) * 64, wn = (w >> 1) * 64;
    const int ll = lane & 15, lh = lane >> 4;
    const int r0 = tid >> 2, kc0 = (tid & 3) * 8;

    f32x4 acc[4][4];
#pragma unroll
    for (int i = 0; i < 4; i++)
#pragma unroll
        for (int j = 0; j < 4; j++) acc[i][j] = f32x4{0.f, 0.f, 0.f, 0.f};

    const size_t aoff = (size_t)(m0 + r0) * Kd + kc0;
    const size_t boff = (size_t)(n0 + r0) * Kd + kc0;
    const size_t roff = (size_t)64 * Kd;

    for (int k0 = 0; k0 < Kd; k0 += 32) {
        __syncthreads();
        gl16(A + aoff + k0,         &As[tid * 8]);
        gl16(A + aoff + roff + k0,  &As[tid * 8 + 2048]);
        gl16(Bt + boff + k0,        &Bs[tid * 8]);
        gl16(Bt + boff + roff + k0, &Bs[tid * 8 + 2048]);
        __syncthreads();

        bf16x8 af[4], bfr[4];
#pragma unroll
        for (int i = 0; i < 4; i++)
            af[i] = *(const bf16x8*)&As[(wm + 16 * i + ll) * 32 + lh * 8];
#pragma unroll
        for (int j = 0; j < 4; j++)
            bfr[j] = *(const bf16x8*)&Bs[(wn + 16 * j + ll) * 32 + lh * 8];
#pragma unroll
        for (int i = 0; i < 4; i++)
#pragma unroll
            for (int j = 0; j < 4; j++)
                acc[i][j] = __builtin_amdgcn_mfma_f32_16x16x32_bf16(af[i], bfr[j], acc[i][j], 0, 0, 0);
    }
#pragma unroll
    for (int i = 0; i < 4; i++)
#pragma unroll
        for (int j = 0; j < 4; j++) {
            ushort_t o4[4];
#pragma unroll
            for (int r = 0; r < 4; r++) o4[r] = f2bf(acc[i][j][r]);
            size_t n = n0 + wn + 16 * j + ll;
            size_t m = m0 + wm + 16 * i + lh * 4;
            *(uint2*)&Ct[n * M + m] = *(uint2*)o4;
        }
}

// ---------------------------------------------------------------------------
// RoPE from hi/lo split Q/K -> bf16 QR/KR
// ---------------------------------------------------------------------------
__global__ __launch_bounds__(256) void rope_split(const ushort_t* __restrict__ Qh,
                                                  const ushort_t* __restrict__ Ql,
                                                  const ushort_t* __restrict__ Kh,
                                                  const ushort_t* __restrict__ Kl,
                                                  ushort_t* __restrict__ QR,
                                                  ushort_t* __restrict__ KR)
{
    int idx = blockIdx.x * 256 + threadIdx.x;
    int s   = idx >> 11;
    int rem = idx & 2047;
    int h   = rem >> 6;
    int d   = rem & 63;
    float inv = exp2f(-0.20762050593046f * (float)d);
    float ang = (float)s * inv;
    float sn, cs;
    sincosf(ang, &sn, &cs);
    size_t base = (size_t)s * E + h * HD;
    float q0 = bf2f(Qh[base + d])      + bf2f(Ql[base + d]);
    float q1 = bf2f(Qh[base + d + 64]) + bf2f(Ql[base + d + 64]);
    QR[base + d]      = f2bf(q0 * cs - q1 * sn);
    QR[base + d + 64] = f2bf(q1 * cs + q0 * sn);
    float k0 = bf2f(Kh[base + d])      + bf2f(Kl[base + d]);
    float k1 = bf2f(Kh[base + d + 64]) + bf2f(Kl[base + d + 64]);
    KR[base + d]      = f2bf(k0 * cs - k1 * sn);
    KR[base + d + 64] = f2bf(k1 * cs + k0 * sn);
}

// ---------------------------------------------------------------------------
// Selection v10 = v8 radix restored (measured best: 419 us).
// 16 q-rows/block, 16 waves (1024 thr), grid (H, S/16).
// LDS-sweep radix: pass-0 ballot-aggregated histogram (zero-skip),
// pass-1 sparse plain atomics. v9's register-resident row REVERTED
// (measured 440 vs 419 -- ballot-chain VALU core is the floor, LDS
// sweeps were not on the critical path).
// ---------------------------------------------------------------------------
__global__ __launch_bounds__(1024, 8) void select_u16(const ushort_t* __restrict__ Qhi,
                                                      const ushort_t* __restrict__ Qlo,
                                                      const ushort_t* __restrict__ Khi,
                                                      const ushort_t* __restrict__ Klo,
                                                      unsigned* __restrict__ Mask)
{
    __shared__ ushort_t sc16[16 * 2048];   // 64 KB; 8B-block xor-swizzle per row
    __shared__ unsigned hist[16][256];     // 16 KB; reused as tie-col list

    const int tid = threadIdx.x;
    const int w = tid >> 6, lane = tid & 63;
    const int ll = lane & 15, lh = lane >> 4;
    const int q0 = blockIdx.y * 16;        // grid transposed: y = q-tile
    const int h  = blockIdx.x;             //                  x = head

    // Q B-frags for rows q0+ll (hi/lo)
    bf16x8 bqh[4], bql[4];
    {
        const size_t qb = (size_t)(q0 + ll) * E + h * HD;
#pragma unroll
        for (int ks = 0; ks < 4; ks++) {
            bqh[ks] = *(const bf16x8*)&Qhi[qb + ks * 32 + lh * 8];
            bql[ks] = *(const bf16x8*)&Qlo[qb + ks * 32 + lh * 8];
        }
    }

    // ---- score phase (no barriers): wave w covers kv strip [cb+16w, +16) ----
    const int qend = q0 + 16;
    for (int cb = 0; cb < qend; cb += 256) {
        const size_t kbase = (size_t)(cb + w * 16 + ll) * E + h * HD;
        f32x4 acc = f32x4{0.f, 0.f, 0.f, 0.f};
#pragma unroll
        for (int ks = 0; ks < 4; ks++) {
            bf16x8 akh = *(const bf16x8*)&Khi[kbase + ks * 32 + lh * 8];
            bf16x8 akl = *(const bf16x8*)&Klo[kbase + ks * 32 + lh * 8];
            acc = __builtin_amdgcn_mfma_f32_16x16x32_bf16(akh, bqh[ks], acc, 0, 0, 0);
            acc = __builtin_amdgcn_mfma_f32_16x16x32_bf16(akh, bql[ks], acc, 0, 0, 0);
            acc = __builtin_amdgcn_mfma_f32_16x16x32_bf16(akl, bqh[ks], acc, 0, 0, 0);
        }
        // C-layout: q col = ll, kv row = w*16 + lh*4 + r
        const int qrow_g = q0 + ll;
        const int col0 = cb + w * 16 + lh * 4;
        ushort_t v4[4];
#pragma unroll
        for (int r = 0; r < 4; r++) {
            int col = col0 + r;
            v4[r] = (col <= qrow_g) ? (ushort_t)(fmap(acc[r]) >> 16) : (ushort_t)0;
        }
        const int blk = col0 >> 2;
        *(uint2*)&sc16[ll * 2048 + ((blk ^ (ll & 7)) << 2)] = *(uint2*)v4;
    }
    __syncthreads();

    // ---- radix + tie + mask: wave w owns q-row w ----
    unsigned* hw = hist[w];
    {
        const int qq = w;
        const int qrow = q0 + qq;
        ushort_t* srow = &sc16[qq * 2048];
        const int swz = qq & 7;
        const int nch = (qrow >> 6) + 1;   // valid 64-col chunks
        unsigned thr = 1u;
        if (qrow + 1 > NKEEP) {
            unsigned p = 0u, need = NKEEP;
#pragma unroll
            for (int pass = 0; pass < 2; pass++) {
                *(uint4*)&hw[lane * 4] = make_uint4(0u, 0u, 0u, 0u);
                __threadfence_block();
                if (pass == 0) {
                    // wave-aggregated high-byte histogram; skip zero sentinels.
                    // One atomicAdd lane-op per unique digit.
                    for (int i = 0; i < nch; i++) {
                        unsigned v = srow[lane + (i << 6)];   // order-agnostic
                        unsigned d = v >> 8;
                        bool part = (v != 0u);
                        unsigned long long mm = __ballot(part);
#pragma unroll
                        for (int b = 0; b < 8; b++) {
                            unsigned long long bb = __ballot((d >> b) & 1u);
                            mm &= ((d >> b) & 1u) ? bb : ~bb;
                        }
                        if (part && ((mm & ((1ull << lane) - 1ull)) == 0ull))
                            atomicAdd(&hw[d], (unsigned)__popcll(mm));
                    }
                } else {
                    for (int i = 0; i < nch; i++) {
                        unsigned v = srow[lane + (i << 6)];
                        if ((v >> 8) == p) atomicAdd(&hw[v & 255u], 1u);
                    }
                }
                __threadfence_block();
                uint4 hv = *(const uint4*)&hw[lane * 4];
                unsigned t3 = hv.w, t2 = t3 + hv.z, t1 = t2 + hv.y, t0 = t1 + hv.x;
                unsigned sv = t0, run = sv;
#pragma unroll
                for (int off = 1; off < 64; off <<= 1) {
                    unsigned o = __shfl_down(run, off);
                    if (lane + off < 64) run += o;
                }
                const unsigned nxt = run - sv;
                unsigned tj[4] = { t0, t1, t2, t3 };
                bool m = false; unsigned nb = 0u, nn = 0u;
#pragma unroll
                for (int j = 0; j < 4; j++) {
                    unsigned sb  = nxt + tj[j];
                    unsigned sb1 = nxt + ((j < 3) ? tj[j + 1] : 0u);
                    if (!m && need <= sb && need > sb1) {
                        m = true; nb = (unsigned)(lane * 4 + j); nn = need - sb1;
                    }
                }
                unsigned long long bal = __ballot(m);
                int src = __ffsll(bal) - 1;
                p    = (p << 8) | __shfl(nb, src);
                need = __shfl(nn, src);
            }
            thr = p;
            const unsigned count_eq = hw[p & 255u];   // pass-2 hist persists
            const unsigned t_need = need;
            if (count_eq > t_need) {
                const bool ovf = (count_eq > 64);
                ushort_t* tiecol = (ushort_t*)hw;     // hist no longer needed
                unsigned tcnt = 0;
                for (int i = 0; i < nch; i++) {
                    int c = lane + (i << 6);
                    int adr = (((c >> 2) ^ swz) << 2) | (c & 3);
                    bool eq = (srow[adr] == (ushort_t)thr);
                    unsigned long long bal = __ballot(eq);
                    if (eq) {
                        unsigned slot = tcnt + (unsigned)__popcll(bal & ((1ull << lane) - 1ull));
                        if (ovf) {
                            if (slot >= t_need) srow[adr] = (ushort_t)(thr - 1u);  // keep-first-by-col fallback
                        } else {
                            tiecol[slot] = (ushort_t)c;
                        }
                    }
                    tcnt += (unsigned)__popcll(bal);
                }
                if (!ovf) {
                    __threadfence_block();
                    const int ntie = (int)count_eq;
                    int mycol = (lane < ntie) ? (int)tiecol[lane] : 0;
                    float myval = 0.f;
                    const size_t qb = (size_t)qrow * E + h * HD;
                    const float qv0 = bf2f(Qhi[qb + lane])      + bf2f(Qlo[qb + lane]);
                    const float qv1 = bf2f(Qhi[qb + lane + 64]) + bf2f(Qlo[qb + lane + 64]);
                    for (int tt = 0; tt < ntie; tt++) {
                        const size_t kb = (size_t)tiecol[tt] * E + h * HD;
                        float kv0 = bf2f(Khi[kb + lane])      + bf2f(Klo[kb + lane]);
                        float kv1 = bf2f(Khi[kb + lane + 64]) + bf2f(Klo[kb + lane + 64]);
                        float pp = qv0 * kv0 + qv1 * kv1;
#pragma unroll
                        for (int off = 1; off < 64; off <<= 1) pp += __shfl_xor(pp, off);
                        if (lane == tt) myval = pp;
                    }
                    int rank = 0;
                    for (int j = 0; j < ntie; j++) {
                        float vj = __shfl(myval, j);
                        int   cj = __shfl(mycol, j);
                        if (lane < ntie && ((vj > myval) || (vj == myval && cj < mycol))) rank++;
                    }
                    if (lane < ntie && rank >= (int)t_need) {
                        int adr = (((mycol >> 2) ^ swz) << 2) | (mycol & 3);
                        srow[adr] = (ushort_t)(thr - 1u);
                    }
                    __threadfence_block();
                }
            }
        }
        // mask write: keep = score >= thr (exactly NKEEP kept for radix rows)
        const size_t mbase = ((size_t)h * S + qrow) * 64;
        for (int ci = 0; ci < nch; ci++) {
            int c = ci * 64 + lane;
            int adr = (((c >> 2) ^ swz) << 2) | (c & 3);
            bool keep = (unsigned)srow[adr] >= thr;
            unsigned long long bm = __ballot(keep);
            if (lane == 0) {
                Mask[mbase + 2 * ci]     = (unsigned)bm;
                Mask[mbase + 2 * ci + 1] = (unsigned)(bm >> 32);
            }
        }
        {   // zero tail chunks (cols > qrow): one pass, lanes cover chunks
            int ci = nch + lane;
            if (ci < 32) {
                Mask[mbase + 2 * ci]     = 0u;
                Mask[mbase + 2 * ci + 1] = 0u;
            }
        }
    }
}

// ---------------------------------------------------------------------------
// MFMA flash attention.
// (1) s_setprio(1) around the QK^T and PV MFMA clusters (T5,
//     attn-regime-proven +4-7% -- independent multi-wave blocks);
// (2) longest-first block order: q0 reversed so high-q0 (costliest,
//     most kv tiles) blocks dispatch first; the 1024-block grid's second
//     scheduling wave then holds only cheap blocks (better tail packing).
// ---------------------------------------------------------------------------
__global__ __launch_bounds__(256) void attn_mfma(const ushort_t* __restrict__ QR,
                                                 const ushort_t* __restrict__ KR,
                                                 const ushort_t* __restrict__ Vt,
                                                 const unsigned* __restrict__ Mask,
                                                 ushort_t* __restrict__ O)
{
    __shared__ ushort_t Qs[64][136];
    __shared__ ushort_t Ks[64][136];
    __shared__ ushort_t Vs[128][72];
    __shared__ unsigned long long Ms[64];

    const int tid = threadIdx.x;
    const int w = tid >> 6, lane = tid & 63;
    const int ll = lane & 15, lh = lane >> 4;
    const int q0 = (gridDim.x - 1 - blockIdx.x) * 64;   // longest-first
    const int h  = blockIdx.y;

#pragma unroll
    for (int i = 0; i < 4; i++) {
        int idx = tid + i * 256;
        int r = idx >> 4, c8 = (idx & 15) * 8;
        *(uint4*)&Qs[r][c8] = *(const uint4*)&QR[(size_t)(q0 + r) * E + h * HD + c8];
    }

    f32x4 Oa[8];
#pragma unroll
    for (int i = 0; i < 8; i++) Oa[i] = f32x4{0.f, 0.f, 0.f, 0.f};
    float mrun = NEGF, lrun = 0.f;
    const float SCL = 0.08838834764831845f * 1.44269504088896f;

    for (int cb = 0; cb <= q0; cb += 64) {
        __syncthreads();
#pragma unroll
        for (int i = 0; i < 4; i++) {
            int idx = tid + i * 256;
            int r = idx >> 4, c8 = (idx & 15) * 8;
            *(uint4*)&Ks[r][c8] = *(const uint4*)&KR[(size_t)(cb + r) * E + h * HD + c8];
        }
#pragma unroll
        for (int i = 0; i < 4; i++) {
            int idx = tid + i * 256;
            int r = idx >> 3, c8 = (idx & 7) * 8;
            *(uint4*)&Vs[r][c8] = *(const uint4*)&Vt[((size_t)h * HD + r) * S + cb + c8];
        }
        if (tid < 64)
            Ms[tid] = *(const unsigned long long*)&Mask[((size_t)h * S + q0 + tid) * 64 + (cb >> 5)];
        __syncthreads();

        f32x4 Sc[4];
#pragma unroll
        for (int t = 0; t < 4; t++) Sc[t] = f32x4{0.f, 0.f, 0.f, 0.f};
        __builtin_amdgcn_s_setprio(1);
#pragma unroll
        for (int kk = 0; kk < 4; kk++) {
            bf16x8 bq = *(const bf16x8*)&Qs[16 * w + ll][kk * 32 + lh * 8];
#pragma unroll
            for (int t = 0; t < 4; t++) {
                bf16x8 ak = *(const bf16x8*)&Ks[t * 16 + ll][kk * 32 + lh * 8];
                Sc[t] = __builtin_amdgcn_mfma_f32_16x16x32_bf16(ak, bq, Sc[t], 0, 0, 0);
            }
        }
        __builtin_amdgcn_s_setprio(0);

        unsigned long long mrow = Ms[16 * w + ll];
        float sc[4][4];
        float cm = NEGF;
#pragma unroll
        for (int t = 0; t < 4; t++)
#pragma unroll
            for (int r = 0; r < 4; r++) {
                int bit = t * 16 + lh * 4 + r;
                float v = ((mrow >> bit) & 1ull) ? Sc[t][r] * SCL : NEGF;
                sc[t][r] = v;
                cm = fmaxf(cm, v);
            }
        cm = fmaxf(cm, __shfl_xor(cm, 16));
        cm = fmaxf(cm, __shfl_xor(cm, 32));
        float mnew = fmaxf(mrun, cm);
        float alpha = exp2f(mrun - mnew);
        mrun = mnew;
        lrun *= alpha;

        unsigned pk[4][2];
#pragma unroll
        for (int t = 0; t < 4; t++) {
            float p0 = (sc[t][0] > -1e37f) ? exp2f(sc[t][0] - mnew) : 0.f;
            float p1 = (sc[t][1] > -1e37f) ? exp2f(sc[t][1] - mnew) : 0.f;
            float p2 = (sc[t][2] > -1e37f) ? exp2f(sc[t][2] - mnew) : 0.f;
            float p3 = (sc[t][3] > -1e37f) ? exp2f(sc[t][3] - mnew) : 0.f;
            lrun += p0 + p1 + p2 + p3;
            pk[t][0] = (unsigned)f2bf(p0) | ((unsigned)f2bf(p1) << 16);
            pk[t][1] = (unsigned)f2bf(p2) | ((unsigned)f2bf(p3) << 16);
        }
#pragma unroll
        for (int dt = 0; dt < 8; dt++) Oa[dt] *= alpha;

#pragma unroll
        for (int ks = 0; ks < 2; ks++) {
            union { unsigned u[4]; bf16x8 v; } bu;
#pragma unroll
            for (int jj = 0; jj < 4; jj++) {
                int rp  = jj & 1;
                int src = ll + 16 * ((lh & 1) * 2 + (jj >> 1));
                unsigned v0 = __shfl(pk[ks * 2][rp], src);
                unsigned v1 = __shfl(pk[ks * 2 + 1][rp], src);
                bu.u[jj] = (lh >> 1) ? v1 : v0;
            }
            bf16x8 bp = bu.v;
            __builtin_amdgcn_s_setprio(1);
#pragma unroll
            for (int dt = 0; dt < 8; dt++) {
                bf16x8 av = *(const bf16x8*)&Vs[dt * 16 + ll][ks * 32 + lh * 8];
                Oa[dt] = __builtin_amdgcn_mfma_f32_16x16x32_bf16(av, bp, Oa[dt], 0, 0, 0);
            }
            __builtin_amdgcn_s_setprio(0);
        }
    }

    lrun += __shfl_xor(lrun, 16);
    lrun += __shfl_xor(lrun, 32);
    float linv = 1.0f / lrun;

    __syncthreads();
    ushort_t* tb = &Ks[16 * w][0];
#pragma unroll
    for (int dt = 0; dt < 8; dt++)
#pragma unroll
        for (int r = 0; r < 4; r++)
            tb[ll * 136 + dt * 16 + lh * 4 + r] = f2bf(Oa[dt][r] * linv);
#pragma unroll
    for (int i = 0; i < 4; i++) {
        int idx = lane + 64 * i;
        int r = idx >> 4, c8 = (idx & 15) * 8;
        uint4 vv = *(const uint4*)&tb[r * 136 + c8];
        *(uint4*)&O[(size_t)(q0 + 16 * w + r) * E + h * HD + c8] = vv;
    }
}

// ---------------------------------------------------------------------------
extern "C" void kernel_launch(void* const* d_in, const int* in_sizes, int n_in,
                              void* d_out, int out_size, void* d_ws, size_t ws_size,
                              hipStream_t stream)
{
    (void)in_sizes; (void)n_in; (void)out_size; (void)ws_size;
    const float* hidden = (const float*)d_in[0];
    const float* Wq = (const float*)d_in[1];
    const float* Wk = (const float*)d_in[2];
    const float* Wv = (const float*)d_in[3];
    const float* Wo = (const float*)d_in[4];

    float* ws = (float*)d_ws;
    const size_t SE = (size_t)S * E;   // 8388608
    ushort_t* Hhi  = (ushort_t*)ws;                      // [0,   .5SE)
    ushort_t* Hlo  = (ushort_t*)(ws + SE / 2);           // [.5,  1SE)  -> later Obf
    ushort_t* WtH  = (ushort_t*)(ws + SE);               // [1,   2SE)  -> later Wt
    ushort_t* WtL  = (ushort_t*)(ws + 2 * SE);           // [2,   3SE)  -> later QR/KR
    ushort_t* Qhi  = (ushort_t*)(ws + 3 * SE);           // [3,  3.5SE)
    ushort_t* Qlo  = (ushort_t*)(ws + 3 * SE + SE / 2);  // [3.5, 4SE)
    ushort_t* Khi  = (ushort_t*)(ws + 4 * SE);           // [4,  4.5SE)
    ushort_t* Klo  = (ushort_t*)(ws + 4 * SE + SE / 2);  // [4.5, 5SE)
    unsigned* Maskb= (unsigned*)(ws + 5 * SE);           // [5,  5.5SE)
    ushort_t* Vtbf = (ushort_t*)(ws + 5 * SE + SE / 2);  // [5.5, 6SE)
    ushort_t* QRbf = WtL;
    ushort_t* KRbf = (ushort_t*)(ws + 2 * SE + SE / 2);
    ushort_t* Obf  = Hlo;
    ushort_t* Wt   = WtH;
    // total = 6 SE floats = 201 MB

    dim3 gg(E / 128, S / 128);           // (32,16) -> 512 blocks, %8==0
    dim3 gt(E / 32, E / 32);             // (128,128)

    decomp<<<SE / 2048, 256, 0, stream>>>(hidden, Hhi, Hlo);

    transp_decomp<<<gt, 256, 0, stream>>>(Wq, WtH, WtL);
    gemm_split<<<gg, 256, 0, stream>>>(Hhi, Hlo, WtH, WtL, Qhi, Qlo, S, E, E);
    transp_decomp<<<gt, 256, 0, stream>>>(Wk, WtH, WtL);
    gemm_split<<<gg, 256, 0, stream>>>(Hhi, Hlo, WtH, WtL, Khi, Klo, S, E, E);

    select_u16<<<dim3(H, S / 16), 1024, 0, stream>>>(Qhi, Qlo, Khi, Klo, Maskb);

    rope_split<<<(S * 2048) / 256, 256, 0, stream>>>(Qhi, Qlo, Khi, Klo, QRbf, KRbf);

    transp_cvt<<<gt, 256, 0, stream>>>(Wv, Wt);
    gemm_bf16_vt<<<gg, 256, 0, stream>>>(Hhi, Wt, Vtbf, S, E, E);

    attn_mfma<<<dim3(S / 64, H), 256, 0, stream>>>(QRbf, KRbf, Vtbf, Maskb, Obf);

    transp_cvt<<<gt, 256, 0, stream>>>(Wo, Wt);
    gemm_bf16t<<<gg, 256, 0, stream>>>(Obf, Wt, (float*)d_out, S, E, E);
}